// Round 12
// baseline (639.854 us; speedup 1.0000x reference)
//
#include <hip/hip_runtime.h>
#include <hip/hip_bf16.h>
#include <math.h>

#define C_DIM 192
#define NH 6
#define HD 32
#define L_WIN 144
#define NWIN 960
#define MROWS (NWIN * L_WIN)   // 138240 window rows
#define NTOK 131040            // 8*91*180 real tokens
#define Z_ 8
#define H_ 91
#define W_ 180
#define HP_ 96
#define WS_REQUIRED 212336640ull

// workspace offsets (bytes)
#define OFF_WBF   0ull                 // bf16 weights + beta
#define OFF_XWC   1048576ull           // bf16 NTOK*192
#define OFF_QKVB  51367936ull          // bf16 MROWS*576 (ends 210,620,416)
#define OFF_ATTNO 1048576ull           // reuse XWC after qkv
#define OFF_X1B   51367936ull          // reuse QKVB after attn
// wbf element offsets (shorts)
#define WO_QKV  0
#define WO_PROJ 110592
#define WO_FC1  147456
#define WO_FC2  294912
#define WO_BETA 442368
#define W_TOTAL 442560

typedef __attribute__((ext_vector_type(8))) short bf16x8;
typedef __attribute__((ext_vector_type(4))) short s16x4;
typedef __attribute__((ext_vector_type(4))) float f32x4;

__device__ __forceinline__ short f2bf(float f) {
    union { __hip_bfloat16 h; short s; } u; u.h = __float2bfloat16(f); return u.s;
}
__device__ __forceinline__ float bf2f(short s) {
    return __uint_as_float(((unsigned int)(unsigned short)s) << 16);
}

// K=16 bf16 MFMA (A/B frag: lane (c,g) holds k = 4g..4g+3) — verified in r10
__device__ __forceinline__ f32x4 mfma16(s16x4 a, s16x4 b, f32x4 c) {
#if __has_builtin(__builtin_amdgcn_mfma_f32_16x16x16bf16_1k)
    return __builtin_amdgcn_mfma_f32_16x16x16bf16_1k(a, b, c, 0, 0, 0);
#else
    f32x4 d;
    asm volatile("v_mfma_f32_16x16x16_bf16 %0, %1, %2, %3"
                 : "=v"(d) : "v"(a), "v"(b), "v"(c));
    return d;
#endif
}

__device__ __forceinline__ int win_token_to_tok(int r) {
    int n = r / L_WIN, l = r - n * L_WIN;
    int wz = n / 240;
    int rem = n - wz * 240;
    int wh = rem / 15;
    int ww = rem - wh * 15;
    int iz = l / 72;
    int r2 = l - iz * 72;
    int ih = r2 / 12;
    int iw = r2 - ih * 12;
    int z = wz * 2 + iz;
    int h = wh * 6 + ih;
    int w = ww * 12 + iw;
    int zp = z + 1; if (zp >= Z_) zp -= Z_;
    int hp = h + 3; if (hp >= HP_) hp -= HP_;
    int wp = w + 6; if (wp >= W_) wp -= W_;
    if (hp >= H_) return -1;
    return (zp * H_ + hp) * W_ + wp;
}

// ---------------- weight conversion: fp32 -> bf16 pool ------------------------
__global__ __launch_bounds__(256)
void wconv_kernel(const float* __restrict__ qw, const float* __restrict__ pw,
                  const float* __restrict__ f1w, const float* __restrict__ f2w,
                  const float* __restrict__ n1b, short* __restrict__ wbf) {
    int i = blockIdx.x * 256 + threadIdx.x;
    if (i >= W_TOTAL) return;
    float v;
    if (i < WO_PROJ)      v = qw[i];
    else if (i < WO_FC1)  v = pw[i - WO_PROJ];
    else if (i < WO_FC2)  v = f1w[i - WO_FC1];
    else if (i < WO_BETA) v = f2w[i - WO_FC2];
    else                  v = n1b[i - WO_BETA];
    wbf[i] = f2bf(v);
}

// ---------------- per-token LayerNorm(norm1) -> bf16 --------------------------
__global__ __launch_bounds__(256)
void ln_tok_kernel(const float* __restrict__ x, const float* __restrict__ g,
                   const float* __restrict__ b, short* __restrict__ xwc) {
    int wave = threadIdx.x >> 6, lane = threadIdx.x & 63;
    int r = blockIdx.x * 4 + wave;
    if (r >= NTOK) return;
    const float* p = x + (size_t)r * C_DIM;
    float v0 = p[lane], v1 = p[lane + 64], v2 = p[lane + 128];
    float s = v0 + v1 + v2;
    float sq = v0 * v0 + v1 * v1 + v2 * v2;
    #pragma unroll
    for (int off = 32; off; off >>= 1) {
        s += __shfl_xor(s, off);
        sq += __shfl_xor(sq, off);
    }
    float m = s * (1.f / 192.f);
    float var = sq * (1.f / 192.f) - m * m;
    float inv = rsqrtf(var + 1e-5f);
    short* o = xwc + (size_t)r * C_DIM;
    o[lane]       = f2bf((v0 - m) * inv * g[lane]       + b[lane]);
    o[lane + 64]  = f2bf((v1 - m) * inv * g[lane + 64]  + b[lane + 64]);
    o[lane + 128] = f2bf((v2 - m) * inv * g[lane + 128] + b[lane + 128]);
}

// ---------------- qkv GEMM -> layout [win][head][{q,k,v}][144][32] ------------
__global__ __launch_bounds__(256)
void qkv_gemm(const short* __restrict__ xwc, const short* __restrict__ wq,
              const short* __restrict__ beta, const float* __restrict__ bias,
              short* __restrict__ qkvb) {
    __shared__ __align__(16) short As[128][196];
    int t = threadIdx.x, w = t >> 6, l = t & 63, g = l >> 4, c = l & 15;
    int bid = blockIdx.x + 9 * blockIdx.y;
    int xcd = bid & 7, sq_ = bid >> 3;
    int bx = sq_ % 9, by = xcd + 8 * (sq_ / 9);
    int row0 = by * 128, col0 = bx * 64;
    int wr = (w >> 1) * 64, wc = (w & 1) * 32;
    const short* wqb = wq + (size_t)(col0 + wc + c) * 192 + g * 8;
    bf16x8 wv[6][2];
    #pragma unroll
    for (int ks = 0; ks < 6; ks++)
        #pragma unroll
        for (int n = 0; n < 2; n++)
            wv[ks][n] = *(const bf16x8*)(wqb + n * 3072 + ks * 32);
    {
        int r = t & 127;
        int th = t >> 7;
        int tok = win_token_to_tok(row0 + r);
        const short* src = (tok >= 0) ? xwc + (size_t)tok * C_DIM : beta;
        #pragma unroll
        for (int i = 0; i < 12; i++) {
            int cidx = th + 2 * i;
            *(bf16x8*)(&As[r][cidx * 8]) = *(const bf16x8*)(src + cidx * 8);
        }
    }
    __syncthreads();
    f32x4 acc[4][2] = {};
    #pragma unroll
    for (int ks = 0; ks < 6; ks++) {
        bf16x8 af[4];
        #pragma unroll
        for (int m = 0; m < 4; m++)
            af[m] = *(const bf16x8*)(&As[wr + 16 * m + c][ks * 32 + g * 8]);
        #pragma unroll
        for (int m = 0; m < 4; m++)
            #pragma unroll
            for (int n = 0; n < 2; n++)
                acc[m][n] = __builtin_amdgcn_mfma_f32_16x16x32_bf16(af[m], wv[ks][n], acc[m][n], 0, 0, 0);
    }
    #pragma unroll
    for (int m = 0; m < 4; m++)
        #pragma unroll
        for (int reg = 0; reg < 4; reg++) {
            int r = row0 + wr + 16 * m + 4 * g + reg;
            int win = r / 144, ll = r - win * 144;
            #pragma unroll
            for (int n = 0; n < 2; n++) {
                int col = col0 + wc + 16 * n + c;
                int sec = col / 192;
                int head = (col - sec * 192) >> 5;
                int d = col & 31;
                size_t dst = ((size_t)(win * 6 + head) * 3 + sec) * 4608 + ll * 32 + d;
                qkvb[dst] = f2bf(acc[m][n][reg] + bias[col]);
            }
        }
}

// ---------------- MFMA attention: 192 threads, 3 waves x 3 m-frags ------------
__global__ __launch_bounds__(192)
void attn_mfma(const short* __restrict__ qkvb, short* __restrict__ attno) {
    __shared__ __align__(16) short Vt[32][168];
    __shared__ __align__(16) short Pl[3][16][168];
    int blk = blockIdx.x;
    int win = blk / NH, head = blk - win * NH;
    int t = threadIdx.x, w = t >> 6, l = t & 63, g = l >> 4, c = l & 15;
    const short* qb = qkvb + (size_t)(win * 6 + head) * 13824;
    const short* kb = qb + 4608;
    const short* vb = qb + 9216;
    for (int ch = t; ch < 576; ch += 192) {
        int kv = ch >> 2, cc = (ch & 3) * 8;
        bf16x8 v = *(const bf16x8*)(vb + kv * 32 + cc);
        #pragma unroll
        for (int j = 0; j < 8; j++) Vt[cc + j][kv] = v[j];
    }
    for (int i = t; i < 32 * 24; i += 192) Vt[i / 24][144 + i % 24] = 0;
    for (int i = l; i < 16 * 24; i += 64) Pl[w][i / 24][144 + i % 24] = 0;
    __syncthreads();

    bf16x8 kf[9];
    #pragma unroll
    for (int n = 0; n < 9; n++)
        kf[n] = *(const bf16x8*)(kb + (16 * n + c) * 32 + g * 8);

    const float scale2 = 0.2550348668f;  // (1/sqrt(32)) * log2(e)
    for (int m = w; m < 9; m += 3) {
        bf16x8 qf = *(const bf16x8*)(qb + (16 * m + c) * 32 + g * 8);
        f32x4 sv[9];
        #pragma unroll
        for (int n = 0; n < 9; n++) {
            f32x4 z = {};
            sv[n] = __builtin_amdgcn_mfma_f32_16x16x32_bf16(qf, kf[n], z, 0, 0, 0);
        }
        float mx[4], rs[4];
        #pragma unroll
        for (int reg = 0; reg < 4; reg++) {
            float v = -1e30f;
            #pragma unroll
            for (int n = 0; n < 9; n++) { sv[n][reg] *= scale2; v = fmaxf(v, sv[n][reg]); }
            #pragma unroll
            for (int off = 1; off <= 8; off <<= 1) v = fmaxf(v, __shfl_xor(v, off));
            mx[reg] = v;
        }
        #pragma unroll
        for (int reg = 0; reg < 4; reg++) {
            float acc = 0.f;
            #pragma unroll
            for (int n = 0; n < 9; n++) {
                float e = exp2f(sv[n][reg] - mx[reg]);
                sv[n][reg] = e;
                acc += e;
            }
            #pragma unroll
            for (int off = 1; off <= 8; off <<= 1) acc += __shfl_xor(acc, off);
            rs[reg] = 1.f / acc;
        }
        #pragma unroll
        for (int n = 0; n < 9; n++)
            #pragma unroll
            for (int reg = 0; reg < 4; reg++)
                Pl[w][4 * g + reg][16 * n + c] = f2bf(sv[n][reg]);
        asm volatile("s_waitcnt lgkmcnt(0)" ::: "memory");
        f32x4 o[2] = {};
        #pragma unroll
        for (int ks = 0; ks < 5; ks++) {
            bf16x8 pa = *(const bf16x8*)(&Pl[w][c][32 * ks + 8 * g]);
            #pragma unroll
            for (int df = 0; df < 2; df++) {
                bf16x8 vv = *(const bf16x8*)(&Vt[16 * df + c][32 * ks + 8 * g]);
                o[df] = __builtin_amdgcn_mfma_f32_16x16x32_bf16(pa, vv, o[df], 0, 0, 0);
            }
        }
        #pragma unroll
        for (int reg = 0; reg < 4; reg++) {
            int grow = win * L_WIN + 16 * m + 4 * g + reg;
            int tok = win_token_to_tok(grow);
            if (tok < 0) continue;
            #pragma unroll
            for (int df = 0; df < 2; df++)
                attno[(size_t)tok * C_DIM + head * HD + 16 * df + c] =
                    f2bf(o[df][reg] * rs[reg]);
        }
    }
}

// ---------------- proj GEMM + residual -> x1 (bf16) ---------------------------
__global__ __launch_bounds__(256)
void proj_gemm(const short* __restrict__ attno, const short* __restrict__ wp,
               const float* __restrict__ bias, const float* __restrict__ x,
               short* __restrict__ x1b) {
    __shared__ __align__(16) short As[128][196];
    int t = threadIdx.x, w = t >> 6, l = t & 63, g = l >> 4, c = l & 15;
    int bid = blockIdx.x + 3 * blockIdx.y;
    int xcd = bid & 7, sq_ = bid >> 3;
    int bx = sq_ % 3, by = xcd + 8 * (sq_ / 3);
    int row0 = by * 128, col0 = bx * 64;
    int wr = (w >> 1) * 64, wc = (w & 1) * 32;
    const short* wpb = wp + (size_t)(col0 + wc + c) * 192 + g * 8;
    bf16x8 wv[6][2];
    #pragma unroll
    for (int ks = 0; ks < 6; ks++)
        #pragma unroll
        for (int n = 0; n < 2; n++)
            wv[ks][n] = *(const bf16x8*)(wpb + n * 3072 + ks * 32);
    {
        int r = t & 127;
        int th = t >> 7;
        int gr = row0 + r;
        #pragma unroll
        for (int i = 0; i < 12; i++) {
            int cidx = th + 2 * i;
            bf16x8 v = {};
            if (gr < NTOK) v = *(const bf16x8*)(attno + (size_t)gr * C_DIM + cidx * 8);
            *(bf16x8*)(&As[r][cidx * 8]) = v;
        }
    }
    __syncthreads();
    f32x4 acc[4][2] = {};
    #pragma unroll
    for (int ks = 0; ks < 6; ks++) {
        bf16x8 af[4];
        #pragma unroll
        for (int m = 0; m < 4; m++)
            af[m] = *(const bf16x8*)(&As[wr + 16 * m + c][ks * 32 + g * 8]);
        #pragma unroll
        for (int m = 0; m < 4; m++)
            #pragma unroll
            for (int n = 0; n < 2; n++)
                acc[m][n] = __builtin_amdgcn_mfma_f32_16x16x32_bf16(af[m], wv[ks][n], acc[m][n], 0, 0, 0);
    }
    #pragma unroll
    for (int m = 0; m < 4; m++)
        #pragma unroll
        for (int reg = 0; reg < 4; reg++) {
            int r = row0 + wr + 16 * m + 4 * g + reg;
            if (r >= NTOK) continue;
            #pragma unroll
            for (int n = 0; n < 2; n++) {
                int col = col0 + wc + 16 * n + c;
                float v = acc[m][n][reg] + bias[col] + x[(size_t)r * C_DIM + col];
                x1b[(size_t)r * C_DIM + col] = f2bf(v);
            }
        }
}

// ---------------- fused MLP v3: token-split waves + LDS-staged weights --------
// 512 thr, 8 waves x 32 tokens (tf=2). Per quarter: stage W1q (192x192, 72KB)
// in LDS -> all waves read it (amortized over 256 tokens); fc1 operand-swapped
// (A=W from LDS, B=x regs); GELU feeds fc2 A-frags DIRECTLY in registers
// (r10-verified mfma16 layout); stage W2q; fc2 B-frags from LDS. XOR-swizzled
// 16B chunks make b128/s16x4 reads bank-even. No Hs exchange, 4 barriers/q.
__global__ __launch_bounds__(512, 2)
void mlp_kernel(const short* __restrict__ x1b, const short* __restrict__ w1,
                const short* __restrict__ w2, const float* __restrict__ b1,
                const float* __restrict__ b2, const float* __restrict__ g2,
                const float* __restrict__ bb2, float* __restrict__ out) {
    __shared__ __align__(16) short Wb[192 * 192];
    int t = threadIdx.x, wid = t >> 6, l = t & 63, g = l >> 4, c = l & 15;
    int tok0 = blockIdx.x * 256 + wid * 32;
    // x fragments: lane (c,g) holds x1[token][g*8..+7] per ks; 2 token-frags
    bf16x8 xf[2][6];
    #pragma unroll
    for (int tf = 0; tf < 2; tf++) {
        int tok = tok0 + tf * 16 + c;
        bool tv = tok < NTOK;
        const short* xp = x1b + (size_t)tok * C_DIM + g * 8;
        #pragma unroll
        for (int ks = 0; ks < 6; ks++)
            xf[tf][ks] = tv ? *(const bf16x8*)(xp + ks * 32) : (bf16x8){};
    }

    f32x4 acc2[12][2] = {};
    s16x4 pa[12][2];
    for (int q = 0; q < 4; q++) {
        // ---- stage W1 quarter (rows q*192.., cols 0..191), chunk-XOR swizzle
        __syncthreads();   // previous quarter's Wb readers done
        #pragma unroll
        for (int i = 0; i < 9; i++) {
            int ch = t + i * 512;
            int row = ch / 24, c16 = ch - row * 24;
            int c16s = c16 ^ (row & 7);
            *(bf16x8*)(&Wb[row * 192 + c16s * 8]) =
                *(const bf16x8*)(w1 + (size_t)(q * 192 + row) * 192 + c16 * 8);
        }
        __syncthreads();
        // ---- fc1 swapped + GELU per-mh (keeps acc1 live-range tiny) ----
        #pragma unroll
        for (int mh = 0; mh < 12; mh++) {
            int row = 16 * mh + c;
            const short* wrow = Wb + row * 192;
            int rs = c & 7;
            f32x4 a0 = {}, a1 = {};
            #pragma unroll
            for (int ks = 0; ks < 6; ks++) {
                int chs = (4 * ks + g) ^ rs;
                bf16x8 wf = *(const bf16x8*)(wrow + chs * 8);
                a0 = __builtin_amdgcn_mfma_f32_16x16x32_bf16(wf, xf[0][ks], a0, 0, 0, 0);
                a1 = __builtin_amdgcn_mfma_f32_16x16x32_bf16(wf, xf[1][ks], a1, 0, 0, 0);
            }
            #pragma unroll
            for (int reg = 0; reg < 4; reg++) {
                float bv = b1[q * 192 + 16 * mh + 4 * g + reg];
                float v0 = a0[reg] + bv, v1 = a1[reg] + bv;
                float u0 = v0 * (1.5957691216f + 0.0713548162f * v0 * v0);
                float u1 = v1 * (1.5957691216f + 0.0713548162f * v1 * v1);
                float e0 = exp2f(-1.4426950409f * u0);
                float e1 = exp2f(-1.4426950409f * u1);
                pa[mh][0][reg] = f2bf(v0 * __builtin_amdgcn_rcpf(1.f + e0));
                pa[mh][1][reg] = f2bf(v1 * __builtin_amdgcn_rcpf(1.f + e1));
            }
        }
        // ---- stage W2 quarter (rows = outcol 0..191, cols q*192..) ----
        __syncthreads();   // fc1 reads of Wb done
        #pragma unroll
        for (int i = 0; i < 9; i++) {
            int ch = t + i * 512;
            int row = ch / 24, c16 = ch - row * 24;
            int c16s = c16 ^ (row & 7);
            *(bf16x8*)(&Wb[row * 192 + c16s * 8]) =
                *(const bf16x8*)(w2 + (size_t)row * 768 + q * 192 + c16 * 8);
        }
        __syncthreads();
        // ---- fc2: acc2[n] += pa . W2q  (mfma16, B from LDS) ----
        #pragma unroll
        for (int n = 0; n < 12; n++) {
            int row = 16 * n + c;
            const short* wrow = Wb + row * 192;
            int rs = c & 7;
            #pragma unroll
            for (int mh = 0; mh < 12; mh++) {
                int chs = (2 * mh + (g >> 1)) ^ rs;
                s16x4 wf = *(const s16x4*)(wrow + chs * 8 + 4 * (g & 1));
                acc2[n][0] = mfma16(pa[mh][0], wf, acc2[n][0]);
                acc2[n][1] = mfma16(pa[mh][1], wf, acc2[n][1]);
            }
        }
    }

    // ---- epilogue (r10-verified): bias + LN(192) + residual ----
    #pragma unroll
    for (int tf = 0; tf < 2; tf++) {
        float hsum[4] = {}, hsq[4] = {};
        #pragma unroll
        for (int n = 0; n < 12; n++) {
            float bb = b2[16 * n + c];
            #pragma unroll
            for (int reg = 0; reg < 4; reg++) {
                float h = acc2[n][tf][reg] + bb;
                acc2[n][tf][reg] = h;
                hsum[reg] += h; hsq[reg] += h * h;
            }
        }
        #pragma unroll
        for (int reg = 0; reg < 4; reg++) {
            #pragma unroll
            for (int off = 1; off <= 8; off <<= 1) {
                hsum[reg] += __shfl_xor(hsum[reg], off);
                hsq[reg]  += __shfl_xor(hsq[reg], off);
            }
        }
        #pragma unroll
        for (int reg = 0; reg < 4; reg++) {
            int tok = tok0 + tf * 16 + 4 * g + reg;
            if (tok >= NTOK) continue;
            float mean = hsum[reg] * (1.f / 192.f);
            float var = hsq[reg] * (1.f / 192.f) - mean * mean;
            float inv = rsqrtf(var + 1e-5f);
            #pragma unroll
            for (int n = 0; n < 12; n++) {
                int col = 16 * n + c;
                float x1v = bf2f(x1b[(size_t)tok * C_DIM + col]);
                out[(size_t)tok * C_DIM + col] =
                    x1v + (acc2[n][tf][reg] - mean) * inv * g2[col] + bb2[col];
            }
        }
    }
}

extern "C" void kernel_launch(void* const* d_in, const int* in_sizes, int n_in,
                              void* d_out, int out_size, void* d_ws, size_t ws_size,
                              hipStream_t stream) {
    const float* x      = (const float*)d_in[0];
    const float* n1g    = (const float*)d_in[1];
    const float* n1b    = (const float*)d_in[2];
    const float* qkv_w  = (const float*)d_in[3];
    const float* qkv_b  = (const float*)d_in[4];
    const float* proj_w = (const float*)d_in[5];
    const float* proj_b = (const float*)d_in[6];
    const float* n2g    = (const float*)d_in[7];
    const float* n2b    = (const float*)d_in[8];
    const float* fc1_w  = (const float*)d_in[9];
    const float* fc1_b_ = (const float*)d_in[10];
    const float* fc2_w  = (const float*)d_in[11];
    const float* fc2_b  = (const float*)d_in[12];
    float* out = (float*)d_out;

    if (ws_size < WS_REQUIRED) return;

    char* ws = (char*)d_ws;
    short* wbf   = (short*)(ws + OFF_WBF);
    short* xwc   = (short*)(ws + OFF_XWC);
    short* qkvb  = (short*)(ws + OFF_QKVB);
    short* attno = (short*)(ws + OFF_ATTNO);
    short* x1b   = (short*)(ws + OFF_X1B);

    wconv_kernel<<<(W_TOTAL + 255) / 256, 256, 0, stream>>>(
        qkv_w, proj_w, fc1_w, fc2_w, n1b, wbf);

    ln_tok_kernel<<<NTOK / 4, 256, 0, stream>>>(x, n1g, n1b, xwc);

    qkv_gemm<<<dim3(9, MROWS / 128), 256, 0, stream>>>(
        xwc, wbf + WO_QKV, wbf + WO_BETA, qkv_b, qkvb);

    attn_mfma<<<NWIN * NH, 192, 0, stream>>>(qkvb, attno);

    proj_gemm<<<dim3(3, (NTOK + 127) / 128), 256, 0, stream>>>(
        attno, wbf + WO_PROJ, proj_b, x, x1b);

    mlp_kernel<<<(NTOK + 255) / 256, 512, 0, stream>>>(
        x1b, wbf + WO_FC1, wbf + WO_FC2, fc1_b_, fc2_b, n2g, n2b, out);
}

// Round 13
// 572.629 us; speedup vs baseline: 1.1174x; 1.1174x over previous
//
#include <hip/hip_runtime.h>
#include <hip/hip_bf16.h>
#include <math.h>

#define C_DIM 192
#define NH 6
#define HD 32
#define L_WIN 144
#define NWIN 960
#define MROWS (NWIN * L_WIN)   // 138240 window rows
#define NTOK 131040            // 8*91*180 real tokens
#define Z_ 8
#define H_ 91
#define W_ 180
#define HP_ 96
#define WS_REQUIRED 212336640ull

// workspace offsets (bytes)
#define OFF_WBF   0ull                 // bf16 weights + beta
#define OFF_XWC   1048576ull           // bf16 NTOK*192
#define OFF_QKVB  51367936ull          // bf16 MROWS*576 (ends 210,620,416)
#define OFF_ATTNO 1048576ull           // reuse XWC after qkv
#define OFF_X1B   51367936ull          // reuse QKVB after attn
// wbf element offsets (shorts)
#define WO_QKV  0
#define WO_PROJ 110592
#define WO_FC1  147456
#define WO_FC2  294912
#define WO_BETA 442368
#define W_TOTAL 442560

typedef __attribute__((ext_vector_type(8))) short bf16x8;
typedef __attribute__((ext_vector_type(4))) short s16x4;
typedef __attribute__((ext_vector_type(4))) float f32x4;

__device__ __forceinline__ short f2bf(float f) {
    union { __hip_bfloat16 h; short s; } u; u.h = __float2bfloat16(f); return u.s;
}
__device__ __forceinline__ float bf2f(short s) {
    return __uint_as_float(((unsigned int)(unsigned short)s) << 16);
}

__device__ __forceinline__ int win_token_to_tok(int r) {
    int n = r / L_WIN, l = r - n * L_WIN;
    int wz = n / 240;
    int rem = n - wz * 240;
    int wh = rem / 15;
    int ww = rem - wh * 15;
    int iz = l / 72;
    int r2 = l - iz * 72;
    int ih = r2 / 12;
    int iw = r2 - ih * 12;
    int z = wz * 2 + iz;
    int h = wh * 6 + ih;
    int w = ww * 12 + iw;
    int zp = z + 1; if (zp >= Z_) zp -= Z_;
    int hp = h + 3; if (hp >= HP_) hp -= HP_;
    int wp = w + 6; if (wp >= W_) wp -= W_;
    if (hp >= H_) return -1;
    return (zp * H_ + hp) * W_ + wp;
}

// ---------------- weight conversion: fp32 -> bf16 pool ------------------------
__global__ __launch_bounds__(256)
void wconv_kernel(const float* __restrict__ qw, const float* __restrict__ pw,
                  const float* __restrict__ f1w, const float* __restrict__ f2w,
                  const float* __restrict__ n1b, short* __restrict__ wbf) {
    int i = blockIdx.x * 256 + threadIdx.x;
    if (i >= W_TOTAL) return;
    float v;
    if (i < WO_PROJ)      v = qw[i];
    else if (i < WO_FC1)  v = pw[i - WO_PROJ];
    else if (i < WO_FC2)  v = f1w[i - WO_FC1];
    else if (i < WO_BETA) v = f2w[i - WO_FC2];
    else                  v = n1b[i - WO_BETA];
    wbf[i] = f2bf(v);
}

// ---------------- per-token LayerNorm(norm1) -> bf16 --------------------------
__global__ __launch_bounds__(256)
void ln_tok_kernel(const float* __restrict__ x, const float* __restrict__ g,
                   const float* __restrict__ b, short* __restrict__ xwc) {
    int wave = threadIdx.x >> 6, lane = threadIdx.x & 63;
    int r = blockIdx.x * 4 + wave;
    if (r >= NTOK) return;
    const float* p = x + (size_t)r * C_DIM;
    float v0 = p[lane], v1 = p[lane + 64], v2 = p[lane + 128];
    float s = v0 + v1 + v2;
    float sq = v0 * v0 + v1 * v1 + v2 * v2;
    #pragma unroll
    for (int off = 32; off; off >>= 1) {
        s += __shfl_xor(s, off);
        sq += __shfl_xor(sq, off);
    }
    float m = s * (1.f / 192.f);
    float var = sq * (1.f / 192.f) - m * m;
    float inv = rsqrtf(var + 1e-5f);
    short* o = xwc + (size_t)r * C_DIM;
    o[lane]       = f2bf((v0 - m) * inv * g[lane]       + b[lane]);
    o[lane + 64]  = f2bf((v1 - m) * inv * g[lane + 64]  + b[lane + 64]);
    o[lane + 128] = f2bf((v2 - m) * inv * g[lane + 128] + b[lane + 128]);
}

// ---------------- qkv GEMM -> layout [win][head][{q,k,v}][144][32] ------------
__global__ __launch_bounds__(256)
void qkv_gemm(const short* __restrict__ xwc, const short* __restrict__ wq,
              const short* __restrict__ beta, const float* __restrict__ bias,
              short* __restrict__ qkvb) {
    __shared__ __align__(16) short As[128][196];
    int t = threadIdx.x, w = t >> 6, l = t & 63, g = l >> 4, c = l & 15;
    int bid = blockIdx.x + 9 * blockIdx.y;
    int xcd = bid & 7, sq_ = bid >> 3;
    int bx = sq_ % 9, by = xcd + 8 * (sq_ / 9);
    int row0 = by * 128, col0 = bx * 64;
    int wr = (w >> 1) * 64, wc = (w & 1) * 32;
    const short* wqb = wq + (size_t)(col0 + wc + c) * 192 + g * 8;
    bf16x8 wv[6][2];
    #pragma unroll
    for (int ks = 0; ks < 6; ks++)
        #pragma unroll
        for (int n = 0; n < 2; n++)
            wv[ks][n] = *(const bf16x8*)(wqb + n * 3072 + ks * 32);
    {
        int r = t & 127;
        int th = t >> 7;
        int tok = win_token_to_tok(row0 + r);
        const short* src = (tok >= 0) ? xwc + (size_t)tok * C_DIM : beta;
        #pragma unroll
        for (int i = 0; i < 12; i++) {
            int cidx = th + 2 * i;
            *(bf16x8*)(&As[r][cidx * 8]) = *(const bf16x8*)(src + cidx * 8);
        }
    }
    __syncthreads();
    f32x4 acc[4][2] = {};
    #pragma unroll
    for (int ks = 0; ks < 6; ks++) {
        bf16x8 af[4];
        #pragma unroll
        for (int m = 0; m < 4; m++)
            af[m] = *(const bf16x8*)(&As[wr + 16 * m + c][ks * 32 + g * 8]);
        #pragma unroll
        for (int m = 0; m < 4; m++)
            #pragma unroll
            for (int n = 0; n < 2; n++)
                acc[m][n] = __builtin_amdgcn_mfma_f32_16x16x32_bf16(af[m], wv[ks][n], acc[m][n], 0, 0, 0);
    }
    #pragma unroll
    for (int m = 0; m < 4; m++)
        #pragma unroll
        for (int reg = 0; reg < 4; reg++) {
            int r = row0 + wr + 16 * m + 4 * g + reg;
            int win = r / 144, ll = r - win * 144;
            #pragma unroll
            for (int n = 0; n < 2; n++) {
                int col = col0 + wc + 16 * n + c;
                int sec = col / 192;
                int head = (col - sec * 192) >> 5;
                int d = col & 31;
                size_t dst = ((size_t)(win * 6 + head) * 3 + sec) * 4608 + ll * 32 + d;
                qkvb[dst] = f2bf(acc[m][n][reg] + bias[col]);
            }
        }
}

// ---------------- MFMA attention: 192 threads, 3 waves x 3 m-frags ------------
__global__ __launch_bounds__(192)
void attn_mfma(const short* __restrict__ qkvb, short* __restrict__ attno) {
    __shared__ __align__(16) short Vt[32][168];
    __shared__ __align__(16) short Pl[3][16][168];
    int blk = blockIdx.x;
    int win = blk / NH, head = blk - win * NH;
    int t = threadIdx.x, w = t >> 6, l = t & 63, g = l >> 4, c = l & 15;
    const short* qb = qkvb + (size_t)(win * 6 + head) * 13824;
    const short* kb = qb + 4608;
    const short* vb = qb + 9216;
    for (int ch = t; ch < 576; ch += 192) {
        int kv = ch >> 2, cc = (ch & 3) * 8;
        bf16x8 v = *(const bf16x8*)(vb + kv * 32 + cc);
        #pragma unroll
        for (int j = 0; j < 8; j++) Vt[cc + j][kv] = v[j];
    }
    for (int i = t; i < 32 * 24; i += 192) Vt[i / 24][144 + i % 24] = 0;
    for (int i = l; i < 16 * 24; i += 64) Pl[w][i / 24][144 + i % 24] = 0;
    __syncthreads();

    bf16x8 kf[9];
    #pragma unroll
    for (int n = 0; n < 9; n++)
        kf[n] = *(const bf16x8*)(kb + (16 * n + c) * 32 + g * 8);

    const float scale2 = 0.2550348668f;  // (1/sqrt(32)) * log2(e)
    for (int m = w; m < 9; m += 3) {
        bf16x8 qf = *(const bf16x8*)(qb + (16 * m + c) * 32 + g * 8);
        f32x4 sv[9];
        #pragma unroll
        for (int n = 0; n < 9; n++) {
            f32x4 z = {};
            sv[n] = __builtin_amdgcn_mfma_f32_16x16x32_bf16(qf, kf[n], z, 0, 0, 0);
        }
        float mx[4], rs[4];
        #pragma unroll
        for (int reg = 0; reg < 4; reg++) {
            float v = -1e30f;
            #pragma unroll
            for (int n = 0; n < 9; n++) { sv[n][reg] *= scale2; v = fmaxf(v, sv[n][reg]); }
            #pragma unroll
            for (int off = 1; off <= 8; off <<= 1) v = fmaxf(v, __shfl_xor(v, off));
            mx[reg] = v;
        }
        #pragma unroll
        for (int reg = 0; reg < 4; reg++) {
            float acc = 0.f;
            #pragma unroll
            for (int n = 0; n < 9; n++) {
                float e = exp2f(sv[n][reg] - mx[reg]);
                sv[n][reg] = e;
                acc += e;
            }
            #pragma unroll
            for (int off = 1; off <= 8; off <<= 1) acc += __shfl_xor(acc, off);
            rs[reg] = 1.f / acc;
        }
        #pragma unroll
        for (int n = 0; n < 9; n++)
            #pragma unroll
            for (int reg = 0; reg < 4; reg++)
                Pl[w][4 * g + reg][16 * n + c] = f2bf(sv[n][reg]);
        asm volatile("s_waitcnt lgkmcnt(0)" ::: "memory");
        f32x4 o[2] = {};
        #pragma unroll
        for (int ks = 0; ks < 5; ks++) {
            bf16x8 pa = *(const bf16x8*)(&Pl[w][c][32 * ks + 8 * g]);
            #pragma unroll
            for (int df = 0; df < 2; df++) {
                bf16x8 vv = *(const bf16x8*)(&Vt[16 * df + c][32 * ks + 8 * g]);
                o[df] = __builtin_amdgcn_mfma_f32_16x16x32_bf16(pa, vv, o[df], 0, 0, 0);
            }
        }
        #pragma unroll
        for (int reg = 0; reg < 4; reg++) {
            int grow = win * L_WIN + 16 * m + 4 * g + reg;
            int tok = win_token_to_tok(grow);
            if (tok < 0) continue;
            #pragma unroll
            for (int df = 0; df < 2; df++)
                attno[(size_t)tok * C_DIM + head * HD + 16 * df + c] =
                    f2bf(o[df][reg] * rs[reg]);
        }
    }
}

// ---------------- proj GEMM + residual -> x1 (bf16) ---------------------------
__global__ __launch_bounds__(256)
void proj_gemm(const short* __restrict__ attno, const short* __restrict__ wp,
               const float* __restrict__ bias, const float* __restrict__ x,
               short* __restrict__ x1b) {
    __shared__ __align__(16) short As[128][196];
    int t = threadIdx.x, w = t >> 6, l = t & 63, g = l >> 4, c = l & 15;
    int bid = blockIdx.x + 3 * blockIdx.y;
    int xcd = bid & 7, sq_ = bid >> 3;
    int bx = sq_ % 3, by = xcd + 8 * (sq_ / 3);
    int row0 = by * 128, col0 = bx * 64;
    int wr = (w >> 1) * 64, wc = (w & 1) * 32;
    const short* wpb = wp + (size_t)(col0 + wc + c) * 192 + g * 8;
    bf16x8 wv[6][2];
    #pragma unroll
    for (int ks = 0; ks < 6; ks++)
        #pragma unroll
        for (int n = 0; n < 2; n++)
            wv[ks][n] = *(const bf16x8*)(wpb + n * 3072 + ks * 32);
    {
        int r = t & 127;
        int th = t >> 7;
        int gr = row0 + r;
        #pragma unroll
        for (int i = 0; i < 12; i++) {
            int cidx = th + 2 * i;
            bf16x8 v = {};
            if (gr < NTOK) v = *(const bf16x8*)(attno + (size_t)gr * C_DIM + cidx * 8);
            *(bf16x8*)(&As[r][cidx * 8]) = v;
        }
    }
    __syncthreads();
    f32x4 acc[4][2] = {};
    #pragma unroll
    for (int ks = 0; ks < 6; ks++) {
        bf16x8 af[4];
        #pragma unroll
        for (int m = 0; m < 4; m++)
            af[m] = *(const bf16x8*)(&As[wr + 16 * m + c][ks * 32 + g * 8]);
        #pragma unroll
        for (int m = 0; m < 4; m++)
            #pragma unroll
            for (int n = 0; n < 2; n++)
                acc[m][n] = __builtin_amdgcn_mfma_f32_16x16x32_bf16(af[m], wv[ks][n], acc[m][n], 0, 0, 0);
    }
    #pragma unroll
    for (int m = 0; m < 4; m++)
        #pragma unroll
        for (int reg = 0; reg < 4; reg++) {
            int r = row0 + wr + 16 * m + 4 * g + reg;
            if (r >= NTOK) continue;
            #pragma unroll
            for (int n = 0; n < 2; n++) {
                int col = col0 + wc + 16 * n + c;
                float v = acc[m][n][reg] + bias[col] + x[(size_t)r * C_DIM + col];
                x1b[(size_t)r * C_DIM + col] = f2bf(v);
            }
        }
}

// ---------------- fused MLP (BM=96, 512 thr, 8 waves = 2 tg x 4 hg) -----------
// Exact round-9 structure (best measured: 226us at BM=128) with the tile
// shrunk 128->96 so LDS drops 104KB -> 78KB => 2 resident blocks/CU
// (4 waves/SIMD). Independent blocks share no barriers -> one block's MFMA
// covers the other's L2/VALU/barrier stalls. Weight traffic only 1.33x r9.
__global__ __launch_bounds__(512, 4)
void mlp_kernel(const short* __restrict__ x1b, const short* __restrict__ w1,
                const short* __restrict__ w2, const float* __restrict__ b1,
                const float* __restrict__ b2, const float* __restrict__ g2,
                const float* __restrict__ bb2, float* __restrict__ out) {
    __shared__ __align__(16) short As[96][196];
    __shared__ __align__(16) short Hs[96][196];
    __shared__ float red_s[96][4];
    __shared__ float red_q[96][4];
    int t = threadIdx.x, w = t >> 6, l = t & 63, g = l >> 4, c = l & 15;
    int tg = w & 1, hg = w >> 1;           // token-group (48 rows), hidden-group (48 cols)
    int row0 = blockIdx.x * 96;            // 131040 = 96 * 1365 exactly
    #pragma unroll
    for (int i = 0; i < 5; i++) {
        int ch = t + i * 512;              // 96 rows x 24 chunks = 2304
        if (ch < 2304) {
            int r = ch / 24, c16 = ch - (ch / 24) * 24;
            *(bf16x8*)(&As[r][c16 * 8]) =
                *(const bf16x8*)(x1b + (size_t)(row0 + r) * C_DIM + c16 * 8);
        }
    }
    __syncthreads();

    f32x4 acc2[3][3] = {};
    for (int q = 0; q < 4; q++) {
        // ---- fc1 (swapped): hidden = q*192 + hg*48 .. +47; tokens tg*48.. ----
        const short* w1b = w1 + (size_t)(q * 192 + hg * 48 + c) * 192 + g * 8;
        f32x4 acc1[3][3] = {};
        bf16x8 cur1[3], nxt1[3];
        #pragma unroll
        for (int mh = 0; mh < 3; mh++) cur1[mh] = *(const bf16x8*)(w1b + mh * 3072);
        #pragma unroll
        for (int ks = 0; ks < 6; ks++) {
            if (ks < 5) {
                #pragma unroll
                for (int mh = 0; mh < 3; mh++)
                    nxt1[mh] = *(const bf16x8*)(w1b + mh * 3072 + (ks + 1) * 32);
            }
            bf16x8 bx[3];
            #pragma unroll
            for (int tn = 0; tn < 3; tn++)
                bx[tn] = *(const bf16x8*)(&As[tg * 48 + 16 * tn + c][ks * 32 + g * 8]);
            #pragma unroll
            for (int mh = 0; mh < 3; mh++)
                #pragma unroll
                for (int tn = 0; tn < 3; tn++)
                    acc1[mh][tn] = __builtin_amdgcn_mfma_f32_16x16x32_bf16(cur1[mh], bx[tn], acc1[mh][tn], 0, 0, 0);
            if (ks < 5) {
                #pragma unroll
                for (int mh = 0; mh < 3; mh++) cur1[mh] = nxt1[mh];
            }
        }
        // ---- hoist fc2's first weight fragments; GELU+barriers hide latency --
        const short* w2b = w2 + (size_t)(hg * 48 + c) * 768 + q * 192 + g * 8;
        bf16x8 cur2[3], nxt2[3];
        #pragma unroll
        for (int n = 0; n < 3; n++) cur2[n] = *(const bf16x8*)(w2b + n * 12288);
        // ---- GELU into packed registers (4 consecutive hidden cols / lane) ---
        s16x4 pk[3][3];
        #pragma unroll
        for (int mh = 0; mh < 3; mh++) {
            float bv[4];
            #pragma unroll
            for (int reg = 0; reg < 4; reg++)
                bv[reg] = b1[q * 192 + hg * 48 + 16 * mh + 4 * g + reg];
            #pragma unroll
            for (int tn = 0; tn < 3; tn++) {
                #pragma unroll
                for (int reg = 0; reg < 4; reg++) {
                    float v = acc1[mh][tn][reg] + bv[reg];
                    float u = v * (1.5957691216f + 0.0713548162f * v * v);
                    float e = exp2f(-1.4426950409f * u);
                    pk[mh][tn][reg] = f2bf(v * __builtin_amdgcn_rcpf(1.f + e));
                }
            }
        }
        __syncthreads();   // previous quarter's fc2 Hs reads complete
        #pragma unroll
        for (int mh = 0; mh < 3; mh++)
            #pragma unroll
            for (int tn = 0; tn < 3; tn++)
                *(s16x4*)(&Hs[tg * 48 + 16 * tn + c][hg * 48 + 16 * mh + 4 * g]) = pk[mh][tn];
        __syncthreads();   // Hs visible to all waves
        // ---- fc2 partial: acc2 += H_q x W2_q (dist-1 cur/nxt) ----------------
        #pragma unroll
        for (int ks = 0; ks < 6; ks++) {
            if (ks < 5) {
                #pragma unroll
                for (int n = 0; n < 3; n++)
                    nxt2[n] = *(const bf16x8*)(w2b + n * 12288 + (ks + 1) * 32);
            }
            bf16x8 pa[3];
            #pragma unroll
            for (int tm = 0; tm < 3; tm++)
                pa[tm] = *(const bf16x8*)(&Hs[tg * 48 + 16 * tm + c][ks * 32 + g * 8]);
            #pragma unroll
            for (int tm = 0; tm < 3; tm++)
                #pragma unroll
                for (int n = 0; n < 3; n++)
                    acc2[tm][n] = __builtin_amdgcn_mfma_f32_16x16x32_bf16(pa[tm], cur2[n], acc2[tm][n], 0, 0, 0);
            if (ks < 5) {
                #pragma unroll
                for (int n = 0; n < 3; n++) cur2[n] = nxt2[n];
            }
        }
    }

    // bias + row stats (wave covers 48 of 192 cols; cross-wave via red arrays)
    #pragma unroll
    for (int tm = 0; tm < 3; tm++)
        #pragma unroll
        for (int reg = 0; reg < 4; reg++) {
            float s = 0.f, sq = 0.f;
            #pragma unroll
            for (int n = 0; n < 3; n++) {
                int col = hg * 48 + 16 * n + c;
                float h = acc2[tm][n][reg] + b2[col];
                acc2[tm][n][reg] = h;
                s += h; sq += h * h;
            }
            #pragma unroll
            for (int off = 1; off <= 8; off <<= 1) {
                s += __shfl_xor(s, off);
                sq += __shfl_xor(sq, off);
            }
            if (c == 0) {
                int q16 = tg * 48 + 16 * tm + 4 * g + reg;
                red_s[q16][hg] = s;
                red_q[q16][hg] = sq;
            }
        }
    __syncthreads();
    #pragma unroll
    for (int tm = 0; tm < 3; tm++)
        #pragma unroll
        for (int reg = 0; reg < 4; reg++) {
            int q16 = tg * 48 + 16 * tm + 4 * g + reg;
            int r = row0 + q16;
            float s = red_s[q16][0] + red_s[q16][1] + red_s[q16][2] + red_s[q16][3];
            float sq = red_q[q16][0] + red_q[q16][1] + red_q[q16][2] + red_q[q16][3];
            float mean = s * (1.f / 192.f);
            float var = sq * (1.f / 192.f) - mean * mean;
            float inv = rsqrtf(var + 1e-5f);
            #pragma unroll
            for (int n = 0; n < 3; n++) {
                int col = hg * 48 + 16 * n + c;
                out[(size_t)r * C_DIM + col] =
                    bf2f(As[q16][col]) + (acc2[tm][n][reg] - mean) * inv * g2[col] + bb2[col];
            }
        }
}

extern "C" void kernel_launch(void* const* d_in, const int* in_sizes, int n_in,
                              void* d_out, int out_size, void* d_ws, size_t ws_size,
                              hipStream_t stream) {
    const float* x      = (const float*)d_in[0];
    const float* n1g    = (const float*)d_in[1];
    const float* n1b    = (const float*)d_in[2];
    const float* qkv_w  = (const float*)d_in[3];
    const float* qkv_b  = (const float*)d_in[4];
    const float* proj_w = (const float*)d_in[5];
    const float* proj_b = (const float*)d_in[6];
    const float* n2g    = (const float*)d_in[7];
    const float* n2b    = (const float*)d_in[8];
    const float* fc1_w  = (const float*)d_in[9];
    const float* fc1_b_ = (const float*)d_in[10];
    const float* fc2_w  = (const float*)d_in[11];
    const float* fc2_b  = (const float*)d_in[12];
    float* out = (float*)d_out;

    if (ws_size < WS_REQUIRED) return;

    char* ws = (char*)d_ws;
    short* wbf   = (short*)(ws + OFF_WBF);
    short* xwc   = (short*)(ws + OFF_XWC);
    short* qkvb  = (short*)(ws + OFF_QKVB);
    short* attno = (short*)(ws + OFF_ATTNO);
    short* x1b   = (short*)(ws + OFF_X1B);

    wconv_kernel<<<(W_TOTAL + 255) / 256, 256, 0, stream>>>(
        qkv_w, proj_w, fc1_w, fc2_w, n1b, wbf);

    ln_tok_kernel<<<NTOK / 4, 256, 0, stream>>>(x, n1g, n1b, xwc);

    qkv_gemm<<<dim3(9, MROWS / 128), 256, 0, stream>>>(
        xwc, wbf + WO_QKV, wbf + WO_BETA, qkv_b, qkvb);

    attn_mfma<<<NWIN * NH, 192, 0, stream>>>(qkvb, attno);

    proj_gemm<<<dim3(3, (NTOK + 127) / 128), 256, 0, stream>>>(
        attno, wbf + WO_PROJ, proj_b, x, x1b);

    mlp_kernel<<<NTOK / 96, 512, 0, stream>>>(
        x1b, wbf + WO_FC1, wbf + WO_FC2, fc1_b_, fc2_b, n2g, n2b, out);
}

// Round 14
// 524.787 us; speedup vs baseline: 1.2193x; 1.0912x over previous
//
#include <hip/hip_runtime.h>
#include <hip/hip_bf16.h>
#include <math.h>

#define C_DIM 192
#define NH 6
#define HD 32
#define L_WIN 144
#define NWIN 960
#define MROWS (NWIN * L_WIN)   // 138240 window rows
#define NTOK 131040            // 8*91*180 real tokens
#define Z_ 8
#define H_ 91
#define W_ 180
#define HP_ 96
#define WS_REQUIRED 212336640ull

// workspace offsets (bytes)
#define OFF_WBF   0ull                 // bf16 weights + beta
#define OFF_XWC   1048576ull           // bf16 NTOK*192
#define OFF_QKVB  51367936ull          // bf16 MROWS*576 (ends 210,620,416)
#define OFF_ATTNO 1048576ull           // reuse XWC after qkv
#define OFF_X1B   51367936ull          // reuse QKVB after attn
// wbf element offsets (shorts)
#define WO_QKV  0
#define WO_PROJ 110592
#define WO_FC1  147456
#define WO_FC2  294912
#define WO_BETA 442368
#define W_TOTAL 442560

typedef __attribute__((ext_vector_type(8))) short bf16x8;
typedef __attribute__((ext_vector_type(4))) short s16x4;
typedef __attribute__((ext_vector_type(4))) float f32x4;

__device__ __forceinline__ short f2bf(float f) {
    union { __hip_bfloat16 h; short s; } u; u.h = __float2bfloat16(f); return u.s;
}
__device__ __forceinline__ float bf2f(short s) {
    return __uint_as_float(((unsigned int)(unsigned short)s) << 16);
}

__device__ __forceinline__ int win_token_to_tok(int r) {
    int n = r / L_WIN, l = r - n * L_WIN;
    int wz = n / 240;
    int rem = n - wz * 240;
    int wh = rem / 15;
    int ww = rem - wh * 15;
    int iz = l / 72;
    int r2 = l - iz * 72;
    int ih = r2 / 12;
    int iw = r2 - ih * 12;
    int z = wz * 2 + iz;
    int h = wh * 6 + ih;
    int w = ww * 12 + iw;
    int zp = z + 1; if (zp >= Z_) zp -= Z_;
    int hp = h + 3; if (hp >= HP_) hp -= HP_;
    int wp = w + 6; if (wp >= W_) wp -= W_;
    if (hp >= H_) return -1;
    return (zp * H_ + hp) * W_ + wp;
}

// ---------------- weight conversion: fp32 -> bf16 pool ------------------------
__global__ __launch_bounds__(256)
void wconv_kernel(const float* __restrict__ qw, const float* __restrict__ pw,
                  const float* __restrict__ f1w, const float* __restrict__ f2w,
                  const float* __restrict__ n1b, short* __restrict__ wbf) {
    int i = blockIdx.x * 256 + threadIdx.x;
    if (i >= W_TOTAL) return;
    float v;
    if (i < WO_PROJ)      v = qw[i];
    else if (i < WO_FC1)  v = pw[i - WO_PROJ];
    else if (i < WO_FC2)  v = f1w[i - WO_FC1];
    else if (i < WO_BETA) v = f2w[i - WO_FC2];
    else                  v = n1b[i - WO_BETA];
    wbf[i] = f2bf(v);
}

// ---------------- per-token LayerNorm(norm1) -> bf16 --------------------------
__global__ __launch_bounds__(256)
void ln_tok_kernel(const float* __restrict__ x, const float* __restrict__ g,
                   const float* __restrict__ b, short* __restrict__ xwc) {
    int wave = threadIdx.x >> 6, lane = threadIdx.x & 63;
    int r = blockIdx.x * 4 + wave;
    if (r >= NTOK) return;
    const float* p = x + (size_t)r * C_DIM;
    float v0 = p[lane], v1 = p[lane + 64], v2 = p[lane + 128];
    float s = v0 + v1 + v2;
    float sq = v0 * v0 + v1 * v1 + v2 * v2;
    #pragma unroll
    for (int off = 32; off; off >>= 1) {
        s += __shfl_xor(s, off);
        sq += __shfl_xor(sq, off);
    }
    float m = s * (1.f / 192.f);
    float var = sq * (1.f / 192.f) - m * m;
    float inv = rsqrtf(var + 1e-5f);
    short* o = xwc + (size_t)r * C_DIM;
    o[lane]       = f2bf((v0 - m) * inv * g[lane]       + b[lane]);
    o[lane + 64]  = f2bf((v1 - m) * inv * g[lane + 64]  + b[lane + 64]);
    o[lane + 128] = f2bf((v2 - m) * inv * g[lane + 128] + b[lane + 128]);
}

// ---------------- qkv GEMM -> layout [win][head][{q,k,v}][144][32] ------------
__global__ __launch_bounds__(256)
void qkv_gemm(const short* __restrict__ xwc, const short* __restrict__ wq,
              const short* __restrict__ beta, const float* __restrict__ bias,
              short* __restrict__ qkvb) {
    __shared__ __align__(16) short As[128][196];
    int t = threadIdx.x, w = t >> 6, l = t & 63, g = l >> 4, c = l & 15;
    int bid = blockIdx.x + 9 * blockIdx.y;
    int xcd = bid & 7, sq_ = bid >> 3;
    int bx = sq_ % 9, by = xcd + 8 * (sq_ / 9);
    int row0 = by * 128, col0 = bx * 64;
    int wr = (w >> 1) * 64, wc = (w & 1) * 32;
    const short* wqb = wq + (size_t)(col0 + wc + c) * 192 + g * 8;
    bf16x8 wv[6][2];
    #pragma unroll
    for (int ks = 0; ks < 6; ks++)
        #pragma unroll
        for (int n = 0; n < 2; n++)
            wv[ks][n] = *(const bf16x8*)(wqb + n * 3072 + ks * 32);
    {
        int r = t & 127;
        int th = t >> 7;
        int tok = win_token_to_tok(row0 + r);
        const short* src = (tok >= 0) ? xwc + (size_t)tok * C_DIM : beta;
        #pragma unroll
        for (int i = 0; i < 12; i++) {
            int cidx = th + 2 * i;
            *(bf16x8*)(&As[r][cidx * 8]) = *(const bf16x8*)(src + cidx * 8);
        }
    }
    __syncthreads();
    f32x4 acc[4][2] = {};
    #pragma unroll
    for (int ks = 0; ks < 6; ks++) {
        bf16x8 af[4];
        #pragma unroll
        for (int m = 0; m < 4; m++)
            af[m] = *(const bf16x8*)(&As[wr + 16 * m + c][ks * 32 + g * 8]);
        #pragma unroll
        for (int m = 0; m < 4; m++)
            #pragma unroll
            for (int n = 0; n < 2; n++)
                acc[m][n] = __builtin_amdgcn_mfma_f32_16x16x32_bf16(af[m], wv[ks][n], acc[m][n], 0, 0, 0);
    }
    #pragma unroll
    for (int m = 0; m < 4; m++)
        #pragma unroll
        for (int reg = 0; reg < 4; reg++) {
            int r = row0 + wr + 16 * m + 4 * g + reg;
            int win = r / 144, ll = r - win * 144;
            #pragma unroll
            for (int n = 0; n < 2; n++) {
                int col = col0 + wc + 16 * n + c;
                int sec = col / 192;
                int head = (col - sec * 192) >> 5;
                int d = col & 31;
                size_t dst = ((size_t)(win * 6 + head) * 3 + sec) * 4608 + ll * 32 + d;
                qkvb[dst] = f2bf(acc[m][n][reg] + bias[col]);
            }
        }
}

// ---------------- MFMA attention: 192 threads, 3 waves x 3 m-frags ------------
__global__ __launch_bounds__(192)
void attn_mfma(const short* __restrict__ qkvb, short* __restrict__ attno) {
    __shared__ __align__(16) short Vt[32][168];
    __shared__ __align__(16) short Pl[3][16][168];
    int blk = blockIdx.x;
    int win = blk / NH, head = blk - win * NH;
    int t = threadIdx.x, w = t >> 6, l = t & 63, g = l >> 4, c = l & 15;
    const short* qb = qkvb + (size_t)(win * 6 + head) * 13824;
    const short* kb = qb + 4608;
    const short* vb = qb + 9216;
    for (int ch = t; ch < 576; ch += 192) {
        int kv = ch >> 2, cc = (ch & 3) * 8;
        bf16x8 v = *(const bf16x8*)(vb + kv * 32 + cc);
        #pragma unroll
        for (int j = 0; j < 8; j++) Vt[cc + j][kv] = v[j];
    }
    for (int i = t; i < 32 * 24; i += 192) Vt[i / 24][144 + i % 24] = 0;
    for (int i = l; i < 16 * 24; i += 64) Pl[w][i / 24][144 + i % 24] = 0;
    __syncthreads();

    bf16x8 kf[9];
    #pragma unroll
    for (int n = 0; n < 9; n++)
        kf[n] = *(const bf16x8*)(kb + (16 * n + c) * 32 + g * 8);

    const float scale2 = 0.2550348668f;  // (1/sqrt(32)) * log2(e)
    for (int m = w; m < 9; m += 3) {
        bf16x8 qf = *(const bf16x8*)(qb + (16 * m + c) * 32 + g * 8);
        f32x4 sv[9];
        #pragma unroll
        for (int n = 0; n < 9; n++) {
            f32x4 z = {};
            sv[n] = __builtin_amdgcn_mfma_f32_16x16x32_bf16(qf, kf[n], z, 0, 0, 0);
        }
        float mx[4], rs[4];
        #pragma unroll
        for (int reg = 0; reg < 4; reg++) {
            float v = -1e30f;
            #pragma unroll
            for (int n = 0; n < 9; n++) { sv[n][reg] *= scale2; v = fmaxf(v, sv[n][reg]); }
            #pragma unroll
            for (int off = 1; off <= 8; off <<= 1) v = fmaxf(v, __shfl_xor(v, off));
            mx[reg] = v;
        }
        #pragma unroll
        for (int reg = 0; reg < 4; reg++) {
            float acc = 0.f;
            #pragma unroll
            for (int n = 0; n < 9; n++) {
                float e = exp2f(sv[n][reg] - mx[reg]);
                sv[n][reg] = e;
                acc += e;
            }
            #pragma unroll
            for (int off = 1; off <= 8; off <<= 1) acc += __shfl_xor(acc, off);
            rs[reg] = 1.f / acc;
        }
        #pragma unroll
        for (int n = 0; n < 9; n++)
            #pragma unroll
            for (int reg = 0; reg < 4; reg++)
                Pl[w][4 * g + reg][16 * n + c] = f2bf(sv[n][reg]);
        asm volatile("s_waitcnt lgkmcnt(0)" ::: "memory");
        f32x4 o[2] = {};
        #pragma unroll
        for (int ks = 0; ks < 5; ks++) {
            bf16x8 pa = *(const bf16x8*)(&Pl[w][c][32 * ks + 8 * g]);
            #pragma unroll
            for (int df = 0; df < 2; df++) {
                bf16x8 vv = *(const bf16x8*)(&Vt[16 * df + c][32 * ks + 8 * g]);
                o[df] = __builtin_amdgcn_mfma_f32_16x16x32_bf16(pa, vv, o[df], 0, 0, 0);
            }
        }
        #pragma unroll
        for (int reg = 0; reg < 4; reg++) {
            int grow = win * L_WIN + 16 * m + 4 * g + reg;
            int tok = win_token_to_tok(grow);
            if (tok < 0) continue;
            #pragma unroll
            for (int df = 0; df < 2; df++)
                attno[(size_t)tok * C_DIM + head * HD + 16 * df + c] =
                    f2bf(o[df][reg] * rs[reg]);
        }
    }
}

// ---------------- proj GEMM + residual -> x1 (bf16) ---------------------------
__global__ __launch_bounds__(256)
void proj_gemm(const short* __restrict__ attno, const short* __restrict__ wp,
               const float* __restrict__ bias, const float* __restrict__ x,
               short* __restrict__ x1b) {
    __shared__ __align__(16) short As[128][196];
    int t = threadIdx.x, w = t >> 6, l = t & 63, g = l >> 4, c = l & 15;
    int bid = blockIdx.x + 3 * blockIdx.y;
    int xcd = bid & 7, sq_ = bid >> 3;
    int bx = sq_ % 3, by = xcd + 8 * (sq_ / 3);
    int row0 = by * 128, col0 = bx * 64;
    int wr = (w >> 1) * 64, wc = (w & 1) * 32;
    const short* wpb = wp + (size_t)(col0 + wc + c) * 192 + g * 8;
    bf16x8 wv[6][2];
    #pragma unroll
    for (int ks = 0; ks < 6; ks++)
        #pragma unroll
        for (int n = 0; n < 2; n++)
            wv[ks][n] = *(const bf16x8*)(wpb + n * 3072 + ks * 32);
    {
        int r = t & 127;
        int th = t >> 7;
        int gr = row0 + r;
        #pragma unroll
        for (int i = 0; i < 12; i++) {
            int cidx = th + 2 * i;
            bf16x8 v = {};
            if (gr < NTOK) v = *(const bf16x8*)(attno + (size_t)gr * C_DIM + cidx * 8);
            *(bf16x8*)(&As[r][cidx * 8]) = v;
        }
    }
    __syncthreads();
    f32x4 acc[4][2] = {};
    #pragma unroll
    for (int ks = 0; ks < 6; ks++) {
        bf16x8 af[4];
        #pragma unroll
        for (int m = 0; m < 4; m++)
            af[m] = *(const bf16x8*)(&As[wr + 16 * m + c][ks * 32 + g * 8]);
        #pragma unroll
        for (int m = 0; m < 4; m++)
            #pragma unroll
            for (int n = 0; n < 2; n++)
                acc[m][n] = __builtin_amdgcn_mfma_f32_16x16x32_bf16(af[m], wv[ks][n], acc[m][n], 0, 0, 0);
    }
    #pragma unroll
    for (int m = 0; m < 4; m++)
        #pragma unroll
        for (int reg = 0; reg < 4; reg++) {
            int r = row0 + wr + 16 * m + 4 * g + reg;
            if (r >= NTOK) continue;
            #pragma unroll
            for (int n = 0; n < 2; n++) {
                int col = col0 + wc + 16 * n + c;
                float v = acc[m][n][reg] + bias[col] + x[(size_t)r * C_DIM + col];
                x1b[(size_t)r * C_DIM + col] = f2bf(v);
            }
        }
}

// ---------------- fused MLP: r6 structure (best measured 211us) + stride 196 --
// BM=64, 256 thr, 4 waves (each: 48 hidden cols x 64 tokens). dist-1 cur/nxt
// weight prefetch (proven best). LDS row stride 196 shorts (= 98 dwords = 2
// mod 32) -> zero bank conflicts (proven in r7). VGPR ~96.
__global__ __launch_bounds__(256)
void mlp_kernel(const short* __restrict__ x1b, const short* __restrict__ w1,
                const short* __restrict__ w2, const float* __restrict__ b1,
                const float* __restrict__ b2, const float* __restrict__ g2,
                const float* __restrict__ bb2, float* __restrict__ out) {
    __shared__ __align__(16) short As[64][196];
    __shared__ __align__(16) short Hs[64][196];
    __shared__ float red_s[64][4];
    __shared__ float red_q[64][4];
    int t = threadIdx.x, w = t >> 6, l = t & 63, g = l >> 4, c = l & 15;
    int row0 = blockIdx.x * 64;
    {
        int r = t & 63, sg = t >> 6;
        int gr = row0 + r;
        #pragma unroll
        for (int i = 0; i < 6; i++) {
            int cidx = sg + 4 * i;
            bf16x8 v = {};
            if (gr < NTOK) v = *(const bf16x8*)(x1b + (size_t)gr * C_DIM + cidx * 8);
            *(bf16x8*)(&As[r][cidx * 8]) = v;
        }
    }
    __syncthreads();

    f32x4 acc2[4][3] = {};
    for (int q = 0; q < 4; q++) {
        // ---- fc1 (operand-swapped): hidden 48w..48w+47, tokens 64 ----------
        const short* w1b = w1 + (size_t)(q * 192 + 48 * w + c) * 192 + g * 8;
        f32x4 acc1[3][4] = {};
        bf16x8 cur1[3], nxt1[3];
        #pragma unroll
        for (int mh = 0; mh < 3; mh++) cur1[mh] = *(const bf16x8*)(w1b + mh * 3072);
        #pragma unroll
        for (int ks = 0; ks < 6; ks++) {
            if (ks < 5) {
                #pragma unroll
                for (int mh = 0; mh < 3; mh++)
                    nxt1[mh] = *(const bf16x8*)(w1b + mh * 3072 + (ks + 1) * 32);
            }
            bf16x8 bx[4];
            #pragma unroll
            for (int tn = 0; tn < 4; tn++)
                bx[tn] = *(const bf16x8*)(&As[16 * tn + c][ks * 32 + g * 8]);
            #pragma unroll
            for (int mh = 0; mh < 3; mh++)
                #pragma unroll
                for (int tn = 0; tn < 4; tn++)
                    acc1[mh][tn] = __builtin_amdgcn_mfma_f32_16x16x32_bf16(cur1[mh], bx[tn], acc1[mh][tn], 0, 0, 0);
            if (ks < 5) {
                #pragma unroll
                for (int mh = 0; mh < 3; mh++) cur1[mh] = nxt1[mh];
            }
        }
        // ---- GELU into packed registers (4 consecutive hidden cols / lane) --
        s16x4 pk[3][4];
        #pragma unroll
        for (int mh = 0; mh < 3; mh++) {
            float bv[4];
            #pragma unroll
            for (int reg = 0; reg < 4; reg++)
                bv[reg] = b1[q * 192 + 48 * w + 16 * mh + 4 * g + reg];
            #pragma unroll
            for (int tn = 0; tn < 4; tn++) {
                #pragma unroll
                for (int reg = 0; reg < 4; reg++) {
                    float v = acc1[mh][tn][reg] + bv[reg];
                    float u = v * (1.5957691216f + 0.0713548162f * v * v);
                    float e = exp2f(-1.4426950409f * u);
                    pk[mh][tn][reg] = f2bf(v * __builtin_amdgcn_rcpf(1.f + e));
                }
            }
        }
        __syncthreads();   // previous quarter's fc2 reads complete
        #pragma unroll
        for (int mh = 0; mh < 3; mh++)
            #pragma unroll
            for (int tn = 0; tn < 4; tn++)
                *(s16x4*)(&Hs[16 * tn + c][48 * w + 16 * mh + 4 * g]) = pk[mh][tn];
        __syncthreads();   // Hs visible to all waves
        // ---- fc2 partial: acc2 += H_q x W2_q (dist-1 cur/nxt) --------------
        const short* w2b = w2 + (size_t)(48 * w + c) * 768 + q * 192 + g * 8;
        bf16x8 cur2[3], nxt2[3];
        #pragma unroll
        for (int n = 0; n < 3; n++) cur2[n] = *(const bf16x8*)(w2b + n * 12288);
        #pragma unroll
        for (int ks = 0; ks < 6; ks++) {
            if (ks < 5) {
                #pragma unroll
                for (int n = 0; n < 3; n++)
                    nxt2[n] = *(const bf16x8*)(w2b + n * 12288 + (ks + 1) * 32);
            }
            bf16x8 pa[4];
            #pragma unroll
            for (int tm = 0; tm < 4; tm++)
                pa[tm] = *(const bf16x8*)(&Hs[16 * tm + c][ks * 32 + g * 8]);
            #pragma unroll
            for (int tm = 0; tm < 4; tm++)
                #pragma unroll
                for (int n = 0; n < 3; n++)
                    acc2[tm][n] = __builtin_amdgcn_mfma_f32_16x16x32_bf16(pa[tm], cur2[n], acc2[tm][n], 0, 0, 0);
            if (ks < 5) {
                #pragma unroll
                for (int n = 0; n < 3; n++) cur2[n] = nxt2[n];
            }
        }
    }

    // bias + row stats + LN + residual
    #pragma unroll
    for (int m = 0; m < 4; m++)
        #pragma unroll
        for (int reg = 0; reg < 4; reg++) {
            float s = 0.f, sq = 0.f;
            #pragma unroll
            for (int n = 0; n < 3; n++) {
                int col = 48 * w + 16 * n + c;
                float h = acc2[m][n][reg] + b2[col];
                acc2[m][n][reg] = h;
                s += h; sq += h * h;
            }
            #pragma unroll
            for (int off = 1; off <= 8; off <<= 1) {
                s += __shfl_xor(s, off);
                sq += __shfl_xor(sq, off);
            }
            if (c == 0) {
                int q16 = 16 * m + 4 * g + reg;
                red_s[q16][w] = s;
                red_q[q16][w] = sq;
            }
        }
    __syncthreads();
    #pragma unroll
    for (int m = 0; m < 4; m++)
        #pragma unroll
        for (int reg = 0; reg < 4; reg++) {
            int q16 = 16 * m + 4 * g + reg;
            int r = row0 + q16;
            float s = red_s[q16][0] + red_s[q16][1] + red_s[q16][2] + red_s[q16][3];
            float sq = red_q[q16][0] + red_q[q16][1] + red_q[q16][2] + red_q[q16][3];
            float mean = s * (1.f / 192.f);
            float var = sq * (1.f / 192.f) - mean * mean;
            float inv = rsqrtf(var + 1e-5f);
            if (r < NTOK) {
                #pragma unroll
                for (int n = 0; n < 3; n++) {
                    int col = 48 * w + 16 * n + c;
                    out[(size_t)r * C_DIM + col] =
                        bf2f(As[q16][col]) + (acc2[m][n][reg] - mean) * inv * g2[col] + bb2[col];
                }
            }
        }
}

extern "C" void kernel_launch(void* const* d_in, const int* in_sizes, int n_in,
                              void* d_out, int out_size, void* d_ws, size_t ws_size,
                              hipStream_t stream) {
    const float* x      = (const float*)d_in[0];
    const float* n1g    = (const float*)d_in[1];
    const float* n1b    = (const float*)d_in[2];
    const float* qkv_w  = (const float*)d_in[3];
    const float* qkv_b  = (const float*)d_in[4];
    const float* proj_w = (const float*)d_in[5];
    const float* proj_b = (const float*)d_in[6];
    const float* n2g    = (const float*)d_in[7];
    const float* n2b    = (const float*)d_in[8];
    const float* fc1_w  = (const float*)d_in[9];
    const float* fc1_b_ = (const float*)d_in[10];
    const float* fc2_w  = (const float*)d_in[11];
    const float* fc2_b  = (const float*)d_in[12];
    float* out = (float*)d_out;

    if (ws_size < WS_REQUIRED) return;

    char* ws = (char*)d_ws;
    short* wbf   = (short*)(ws + OFF_WBF);
    short* xwc   = (short*)(ws + OFF_XWC);
    short* qkvb  = (short*)(ws + OFF_QKVB);
    short* attno = (short*)(ws + OFF_ATTNO);
    short* x1b   = (short*)(ws + OFF_X1B);

    wconv_kernel<<<(W_TOTAL + 255) / 256, 256, 0, stream>>>(
        qkv_w, proj_w, fc1_w, fc2_w, n1b, wbf);

    ln_tok_kernel<<<NTOK / 4, 256, 0, stream>>>(x, n1g, n1b, xwc);

    qkv_gemm<<<dim3(9, MROWS / 128), 256, 0, stream>>>(
        xwc, wbf + WO_QKV, wbf + WO_BETA, qkv_b, qkvb);

    attn_mfma<<<NWIN * NH, 192, 0, stream>>>(qkvb, attno);

    proj_gemm<<<dim3(3, (NTOK + 127) / 128), 256, 0, stream>>>(
        attno, wbf + WO_PROJ, proj_b, x, x1b);

    mlp_kernel<<<(NTOK + 63) / 64, 256, 0, stream>>>(
        x1b, wbf + WO_FC1, wbf + WO_FC2, fc1_b_, fc2_b, n2g, n2b, out);
}